// Round 1
// baseline (2103.900 us; speedup 1.0000x reference)
//
#include <hip/hip_runtime.h>
#include <math.h>
#include <stdint.h>

// Problem constants
static const int VOC  = 32000;
static const int VT_  = 32100;
#define NSLICE 14   // blocks per batch row in k_seq
#define HTRI   19   // h-outputs per slice (last slice gets 9)

typedef __attribute__((ext_vector_type(8))) short bf16x8_t;
typedef __attribute__((ext_vector_type(4))) float f32x4_t;

__device__ __forceinline__ unsigned short f2bf(float f) {
  union { float f; unsigned int u; } v; v.f = f;
  unsigned int u = v.u;
  u = u + 0x7FFFu + ((u >> 16) & 1u);   // RNE
  return (unsigned short)(u >> 16);
}

// ---------------------------------------------------------------- utilities
__global__ void k_zero(int* p, int n) {
  int i = blockIdx.x * blockDim.x + threadIdx.x;
  if (i < n) p[i] = 0;
}

__global__ void k_conv(const float* __restrict__ src, unsigned short* __restrict__ dst, int n4) {
  int i = blockIdx.x * blockDim.x + threadIdx.x;
  int stride = gridDim.x * blockDim.x;
  for (; i < n4; i += stride) {
    float4 f = ((const float4*)src)[i];
    ushort4 o;
    o.x = f2bf(f.x); o.y = f2bf(f.y); o.z = f2bf(f.z); o.w = f2bf(f.w);
    ((ushort4*)dst)[i] = o;
  }
}

// enc_scores = tanh(encoded @ Wo^T + Wo_b): M=4096 (b,s), N=256, K=512
__global__ __launch_bounds__(256) void k_enc(const float* __restrict__ enc,
                                             const float* __restrict__ wo,
                                             const float* __restrict__ wob,
                                             float* __restrict__ outp) {
  int bm = blockIdx.x, bn = blockIdx.y;
  int tid = threadIdx.x;
  int ti = tid & 15, tj = tid >> 4;
  int r0 = bm * 64 + ti * 4;
  int n0 = bn * 64 + tj * 4;
  const float4* A[4]; const float4* B[4];
#pragma unroll
  for (int i = 0; i < 4; i++) A[i] = (const float4*)(enc + (size_t)(r0 + i) * 512);
#pragma unroll
  for (int j = 0; j < 4; j++) B[j] = (const float4*)(wo + (size_t)(n0 + j) * 512);
  float acc[4][4];
#pragma unroll
  for (int i = 0; i < 4; i++)
#pragma unroll
    for (int j = 0; j < 4; j++) acc[i][j] = 0.f;
  for (int k = 0; k < 128; k++) {
    float4 a[4], b[4];
#pragma unroll
    for (int i = 0; i < 4; i++) a[i] = A[i][k];
#pragma unroll
    for (int j = 0; j < 4; j++) b[j] = B[j][k];
#pragma unroll
    for (int i = 0; i < 4; i++)
#pragma unroll
      for (int j = 0; j < 4; j++)
        acc[i][j] += a[i].x * b[j].x + a[i].y * b[j].y + a[i].z * b[j].z + a[i].w * b[j].w;
  }
#pragma unroll
  for (int i = 0; i < 4; i++)
#pragma unroll
    for (int j = 0; j < 4; j++)
      outp[(size_t)(r0 + i) * 256 + n0 + j] = tanhf(acc[i][j] + wob[n0 + j]);
}

// Xg = embed[inputs] @ Wih[:, :256]^T + b_ih: M=2048, N=768, K=256
__global__ __launch_bounds__(256) void k_xg(const float* __restrict__ embed,
                                            const int* __restrict__ inputs,
                                            const float* __restrict__ wih,
                                            const float* __restrict__ bih,
                                            float* __restrict__ xg) {
  int bm = blockIdx.x, bn = blockIdx.y;
  int tid = threadIdx.x;
  int ti = tid & 15, tj = tid >> 4;
  int r0 = bm * 64 + ti * 4;
  int n0 = bn * 64 + tj * 4;
  const float4* A[4]; const float4* B[4];
#pragma unroll
  for (int i = 0; i < 4; i++) A[i] = (const float4*)(embed + (size_t)inputs[r0 + i] * 256);
#pragma unroll
  for (int j = 0; j < 4; j++) B[j] = (const float4*)(wih + (size_t)(n0 + j) * 768);
  float acc[4][4];
#pragma unroll
  for (int i = 0; i < 4; i++)
#pragma unroll
    for (int j = 0; j < 4; j++) acc[i][j] = 0.f;
  for (int k = 0; k < 64; k++) {
    float4 a[4], b[4];
#pragma unroll
    for (int i = 0; i < 4; i++) a[i] = A[i][k];
#pragma unroll
    for (int j = 0; j < 4; j++) b[j] = B[j][k];
#pragma unroll
    for (int i = 0; i < 4; i++)
#pragma unroll
      for (int j = 0; j < 4; j++)
        acc[i][j] += a[i].x * b[j].x + a[i].y * b[j].y + a[i].z * b[j].z + a[i].w * b[j].w;
  }
#pragma unroll
  for (int i = 0; i < 4; i++)
#pragma unroll
    for (int j = 0; j < 4; j++)
      xg[(size_t)(r0 + i) * 768 + n0 + j] = acc[i][j] + bih[n0 + j];
}

// s0 = encoded[:, -1, :] @ bridge^T
__global__ __launch_bounds__(256) void k_s0(const float* __restrict__ enc,
                                            const float* __restrict__ bw,
                                            float* __restrict__ s0) {
  int b = blockIdx.x, h = threadIdx.x;
  const float4* a4 = (const float4*)(enc + ((size_t)b * 128 + 127) * 512);
  const float4* w4 = (const float4*)(bw + (size_t)h * 512);
  float acc = 0.f;
  for (int k = 0; k < 128; k++) {
    float4 a = a4[k], w = w4[k];
    acc += a.x * w.x + a.y * w.y + a.z * w.z + a.w * w.w;
  }
  s0[b * 256 + h] = acc;
}

// ENC_ih[b,s,:] = encoded[b,s,:] @ Wih[:, 256:768]^T  -- only where token ever matches
__global__ __launch_bounds__(256) void k_encih(const float* __restrict__ enc,
                                               const float* __restrict__ wih,
                                               const int* __restrict__ encidx,
                                               const int* __restrict__ inputs,
                                               float* __restrict__ encih) {
  __shared__ int flag;
  int bs = blockIdx.x;
  int b = bs >> 7;
  int tid = threadIdx.x;
  int idx = encidx[bs];
  if (tid < 64) {
    unsigned long long m = __ballot(inputs[b * 64 + tid] == idx);
    if (tid == 0) flag = (m != 0ULL);
  }
  __syncthreads();
  if (!flag) return;
  const float4* e4 = (const float4*)(enc + (size_t)bs * 512);
  for (int d = tid; d < 768; d += 256) {
    const float4* w4 = (const float4*)(wih + (size_t)d * 768 + 256);
    float acc = 0.f;
    for (int k = 0; k < 128; k++) {
      float4 e = e4[k], w = w4[k];
      acc += e.x * w.x + e.y * w.y + e.z * w.z + e.w * w.w;
    }
    encih[(size_t)bs * 768 + d] = acc;
  }
}

// -------------------------------------------------------- sequential GRU
// 448 blocks = 32 batch rows x 14 weight slices (LDS-resident w_hh slice).
// Per step: partial gh dots -> gates -> write s_t slice -> cross-slice barrier
// (monotonic per-(b,t) counter, agent scope) -> masked-softmax cw -> CtxG slice.
__global__ __launch_bounds__(256, 2) void k_seq(
    const float* __restrict__ whh, const float* __restrict__ bhh,
    const float* __restrict__ xg, const float* __restrict__ encsc,
    const float* __restrict__ encih, const int* __restrict__ encidx,
    const int* __restrict__ inputs, const float* __restrict__ s0,
    float* __restrict__ S32, unsigned short* __restrict__ S16, int* __restrict__ cnt) {
  __shared__ float wlds[HTRI * 3 * 260];  // row stride 260 floats (16B aligned, spreads banks)
  __shared__ float sbuf[256];
  __shared__ float ctxg[HTRI * 3];
  __shared__ float ghs[HTRI * 3];
  __shared__ float psis[128];
  __shared__ int mlist[128];
  __shared__ int mcnt_sh;
  int slice = blockIdx.x >> 5;  // 0..13
  int b = blockIdx.x & 31;
  int h0 = slice * HTRI;
  int nh = 256 - h0; if (nh > HTRI) nh = HTRI;
  int nrows = nh * 3;
  int tid = threadIdx.x;
  // stage w_hh slice: local row rr = hl*3+g  <->  global row g*256 + h0 + hl
  for (int idx = tid; idx < nrows * 256; idx += 256) {
    int rr = idx >> 8, k = idx & 255;
    int hl = rr / 3, g = rr - hl * 3;
    wlds[rr * 260 + k] = whh[(size_t)(g * 256 + h0 + hl) * 256 + k];
  }
  sbuf[tid] = s0[b * 256 + tid];
  for (int i = tid; i < nrows; i += 256) ctxg[i] = 0.f;
  __syncthreads();
  int drow = tid >> 2, dpart = tid & 3;
  for (int t = 0; t < 64; t++) {
    int r = b * 64 + t;
    // --- gh partial dots (4 threads per output row, 64 k each)
    float acc = 0.f;
    if (drow < nrows) {
      const float4* w4 = (const float4*)(wlds + drow * 260 + dpart * 64);
      const float4* s4 = (const float4*)(sbuf + dpart * 64);
#pragma unroll
      for (int i = 0; i < 16; i++) {
        float4 w = w4[i], s = s4[i];
        acc += w.x * s.x + w.y * s.y + w.z * s.z + w.w * s.w;
      }
    }
    acc += __shfl_xor(acc, 1);
    acc += __shfl_xor(acc, 2);
    if (drow < nrows && dpart == 0) ghs[drow] = acc;
    __syncthreads();
    // --- gates
    if (tid < nh) {
      int h = h0 + tid;
      float hr = ghs[tid * 3 + 0] + bhh[h];
      float hz = ghs[tid * 3 + 1] + bhh[256 + h];
      float hn = ghs[tid * 3 + 2] + bhh[512 + h];
      float gr = xg[(size_t)r * 768 + h]       + ctxg[tid * 3 + 0];
      float gz = xg[(size_t)r * 768 + 256 + h] + ctxg[tid * 3 + 1];
      float gn = xg[(size_t)r * 768 + 512 + h] + ctxg[tid * 3 + 2];
      float rg = 1.f / (1.f + expf(-(gr + hr)));
      float zg = 1.f / (1.f + expf(-(gz + hz)));
      float ng = tanhf(gn + rg * hn);
      float sn = (1.f - zg) * ng + zg * sbuf[h];
      S32[(size_t)r * 256 + h] = sn;
      S16[(size_t)r * 256 + h] = f2bf(sn);
    }
    __syncthreads();
    // --- cross-slice barrier for this (b,t)
    if (tid == 0) {
      __threadfence();
      __hip_atomic_fetch_add(cnt + r, 1, __ATOMIC_RELEASE, __HIP_MEMORY_SCOPE_AGENT);
      while (__hip_atomic_load(cnt + r, __ATOMIC_RELAXED, __HIP_MEMORY_SCOPE_AGENT) < NSLICE) { }
      __threadfence();
    }
    __syncthreads();
    if (t == 63) break;
    // --- reload full s_t, build matched list for cw(t)
    sbuf[tid] = S32[(size_t)r * 256 + tid];
    if (tid == 0) mcnt_sh = 0;
    __syncthreads();
    int inp_t = inputs[b * 64 + t];
    if (tid < 128) {
      if (encidx[b * 128 + tid] == inp_t) {
        int p = atomicAdd(&mcnt_sh, 1);
        mlist[p] = tid;
      }
    }
    __syncthreads();
    int mc = mcnt_sh;
    if (mc == 0) {
      for (int i = tid; i < nrows; i += 256) ctxg[i] = 0.f;
    } else {
      if (tid < 64) {
        for (int j = 0; j < mc; j++) {
          int s = mlist[j];
          const float4* e4 = (const float4*)(encsc + (size_t)(b * 128 + s) * 256);
          const float4* s4 = (const float4*)sbuf;
          float4 ev = e4[tid], sv = s4[tid];
          float v = ev.x * sv.x + ev.y * sv.y + ev.z * sv.z + ev.w * sv.w;
#pragma unroll
          for (int off = 32; off >= 1; off >>= 1) v += __shfl_down(v, off);
          if (tid == 0) psis[j] = v + (encidx[b * 128 + s] == 0 ? -1000.f : 0.f);
        }
      }
      __syncthreads();
      if (tid == 0) {
        float m = -3e38f;
        for (int j = 0; j < mc; j++) m = fmaxf(m, psis[j]);
        if (m < -500.f) {       // all matches are pads -> reference cw == 0
          for (int j = 0; j < mc; j++) psis[j] = 0.f;
        } else {
          float ss = 0.f;
          for (int j = 0; j < mc; j++) { float e = expf(psis[j] - m); psis[j] = e; ss += e; }
          float rs = 1.f / ss;
          for (int j = 0; j < mc; j++) psis[j] *= rs;
        }
      }
      __syncthreads();
      for (int i = tid; i < nrows; i += 256) {
        int hl = i / 3, g = i - hl * 3;
        int row = g * 256 + h0 + hl;
        float v = 0.f;
        for (int j = 0; j < mc; j++) v += psis[j] * encih[(size_t)(b * 128 + mlist[j]) * 768 + row];
        ctxg[i] = v;
      }
    }
    __syncthreads();
  }
}

// psi_c for all (b,t,s) + pad mask + per-row partial (chunk 250)
__global__ __launch_bounds__(256) void k_psic(const float* __restrict__ S32,
                                              const float* __restrict__ encsc,
                                              const int* __restrict__ encidx,
                                              float* __restrict__ psic,
                                              float* __restrict__ pmax,
                                              float* __restrict__ psum) {
  __shared__ float vals[8][128];
  int r0 = blockIdx.x * 8;
  int tid = threadIdx.x;
#pragma unroll
  for (int it = 0; it < 4; it++) {
    int idx = it * 256 + tid;
    int rl = idx >> 7, s = idx & 127;
    int r = r0 + rl, b = r >> 6;
    const float4* a4 = (const float4*)(S32 + (size_t)r * 256);
    const float4* e4 = (const float4*)(encsc + (size_t)(b * 128 + s) * 256);
    float acc = 0.f;
    for (int k = 0; k < 64; k++) {
      float4 a = a4[k], e = e4[k];
      acc += a.x * e.x + a.y * e.y + a.z * e.z + a.w * e.w;
    }
    if (encidx[b * 128 + s] == 0) acc -= 1000.f;
    psic[(size_t)r * 128 + s] = acc;
    vals[rl][s] = acc;
  }
  __syncthreads();
  if (tid < 8) {
    int r = r0 + tid;
    float m = -3e38f;
    for (int s = 0; s < 128; s++) m = fmaxf(m, vals[tid][s]);
    float ss = 0.f;
    for (int s = 0; s < 128; s++) ss += expf(vals[tid][s] - m);
    pmax[(size_t)r * 256 + 250] = m;
    psum[(size_t)r * 256 + 250] = ss;
  }
}

// psi_g pass A: 128x128 bf16 MFMA tile -> per-row (max, sumexp) partials
__global__ __launch_bounds__(256) void k_p2a(const unsigned short* __restrict__ S16,
                                             const unsigned short* __restrict__ WG16,
                                             const float* __restrict__ wgb,
                                             float* __restrict__ pmax,
                                             float* __restrict__ psum) {
  __shared__ unsigned short lA[128 * 64];
  __shared__ unsigned short lB[128 * 64];
  __shared__ float redm[128][2];
  __shared__ float reds[128][2];
  int nc = blockIdx.x, mt = blockIdx.y;
  int tid = threadIdx.x;
  int wid = tid >> 6, lane = tid & 63;
  int wm = wid >> 1, wn = wid & 1;
  int quad = lane >> 4, l15 = lane & 15;
  f32x4_t acc[4][4];
#pragma unroll
  for (int i = 0; i < 4; i++)
#pragma unroll
    for (int j = 0; j < 4; j++) acc[i][j] = (f32x4_t){0.f, 0.f, 0.f, 0.f};
  for (int kt = 0; kt < 4; kt++) {
#pragma unroll
    for (int u = 0; u < 4; u++) {
      int c = u * 256 + tid;
      int row = c >> 3, ko = (c & 7) * 8;
      __builtin_amdgcn_global_load_lds(
          (const __attribute__((address_space(1))) unsigned int*)(S16 + (size_t)(mt * 128 + row) * 256 + kt * 64 + ko),
          (__attribute__((address_space(3))) unsigned int*)(lA + c * 8), 16, 0, 0);
      __builtin_amdgcn_global_load_lds(
          (const __attribute__((address_space(1))) unsigned int*)(WG16 + (size_t)(nc * 128 + row) * 256 + kt * 64 + ko),
          (__attribute__((address_space(3))) unsigned int*)(lB + c * 8), 16, 0, 0);
    }
    __syncthreads();
#pragma unroll
    for (int ks = 0; ks < 2; ks++) {
      bf16x8_t af[4], bfr[4];
#pragma unroll
      for (int i = 0; i < 4; i++) af[i] = *(const bf16x8_t*)(lA + (wm * 64 + i * 16 + l15) * 64 + ks * 32 + quad * 8);
#pragma unroll
      for (int j = 0; j < 4; j++) bfr[j] = *(const bf16x8_t*)(lB + (wn * 64 + j * 16 + l15) * 64 + ks * 32 + quad * 8);
#pragma unroll
      for (int i = 0; i < 4; i++)
#pragma unroll
        for (int j = 0; j < 4; j++)
          acc[i][j] = __builtin_amdgcn_mfma_f32_16x16x32_bf16(af[i], bfr[j], acc[i][j], 0, 0, 0);
    }
    __syncthreads();
  }
  float bj[4];
#pragma unroll
  for (int j = 0; j < 4; j++) bj[j] = wgb[nc * 128 + wn * 64 + j * 16 + l15];
#pragma unroll
  for (int i = 0; i < 4; i++) {
#pragma unroll
    for (int p = 0; p < 4; p++) {
      float m = -3e38f;
#pragma unroll
      for (int j = 0; j < 4; j++) m = fmaxf(m, acc[i][j][p] + bj[j]);
#pragma unroll
      for (int off = 1; off < 16; off <<= 1) m = fmaxf(m, __shfl_xor(m, off));
      float sum = 0.f;
#pragma unroll
      for (int j = 0; j < 4; j++) sum += expf(acc[i][j][p] + bj[j] - m);
#pragma unroll
      for (int off = 1; off < 16; off <<= 1) sum += __shfl_xor(sum, off);
      if (l15 == 0) {
        int row = wm * 64 + i * 16 + quad * 4 + p;
        redm[row][wn] = m;
        reds[row][wn] = sum;
      }
    }
  }
  __syncthreads();
  if (tid < 128) {
    float m0 = redm[tid][0], m1 = redm[tid][1];
    float M = fmaxf(m0, m1);
    float S = reds[tid][0] * expf(m0 - M) + reds[tid][1] * expf(m1 - M);
    int rg = mt * 128 + tid;
    pmax[(size_t)rg * 256 + nc] = M;
    psum[(size_t)rg * 256 + nc] = S;
  }
}

// merge 251 chunk partials -> per-row (M, Z)
__global__ __launch_bounds__(256) void k_p2m(const float* __restrict__ pmax,
                                             const float* __restrict__ psum,
                                             float* __restrict__ MZ) {
  __shared__ float rm[4], rs[4];
  __shared__ float Msh;
  int r = blockIdx.x, tid = threadIdx.x;
  float m = (tid < 251) ? pmax[(size_t)r * 256 + tid] : -3e38f;
  float mm = m;
#pragma unroll
  for (int off = 32; off >= 1; off >>= 1) mm = fmaxf(mm, __shfl_xor(mm, off));
  if ((tid & 63) == 0) rm[tid >> 6] = mm;
  __syncthreads();
  if (tid == 0) Msh = fmaxf(fmaxf(rm[0], rm[1]), fmaxf(rm[2], rm[3]));
  __syncthreads();
  float M = Msh;
  float z = (tid < 251) ? psum[(size_t)r * 256 + tid] * expf(m - M) : 0.f;
#pragma unroll
  for (int off = 32; off >= 1; off >>= 1) z += __shfl_xor(z, off);
  if ((tid & 63) == 0) rs[tid >> 6] = z;
  __syncthreads();
  if (tid == 0) {
    MZ[2 * r] = M;
    MZ[2 * r + 1] = rs[0] + rs[1] + rs[2] + rs[3];
  }
}

// pass B: recompute psi_g tile, p = exp(psi-M)/Z, write out; chunk-local scatter
// (plain per-row RMW after __syncthreads -- no atomics, no cross-block aliasing)
__global__ __launch_bounds__(256) void k_p2b(const unsigned short* __restrict__ S16,
                                             const unsigned short* __restrict__ WG16,
                                             const float* __restrict__ wgb,
                                             const float* __restrict__ MZ,
                                             const float* __restrict__ psic,
                                             const int* __restrict__ encidx,
                                             float* __restrict__ outp) {
  int nc = blockIdx.x, mt = blockIdx.y;
  int tid = threadIdx.x;
  if (nc == 250) {  // OOV columns [32000, 32100)
    for (int p = tid; p < 128 * 100; p += 256) {
      int rl = p / 100, c2 = p - rl * 100;
      int rg = mt * 128 + rl;
      outp[(size_t)rg * VT_ + 32000 + c2] = 1e-4f;
    }
    __syncthreads();
    if (tid < 128) {
      int rg = mt * 128 + tid, b = rg >> 6;
      float M = MZ[2 * rg];
      float iZ = 1.f / MZ[2 * rg + 1];
      for (int s = 0; s < 128; s++) {
        int idx = encidx[b * 128 + s];
        if (idx >= 32000) {
          float v = expf(psic[(size_t)rg * 128 + s] - M) * iZ;
          outp[(size_t)rg * VT_ + idx] += v;
        }
      }
    }
    return;
  }
  __shared__ unsigned short lA[128 * 64];
  __shared__ unsigned short lB[128 * 64];
  int wid = tid >> 6, lane = tid & 63;
  int wm = wid >> 1, wn = wid & 1;
  int quad = lane >> 4, l15 = lane & 15;
  f32x4_t acc[4][4];
#pragma unroll
  for (int i = 0; i < 4; i++)
#pragma unroll
    for (int j = 0; j < 4; j++) acc[i][j] = (f32x4_t){0.f, 0.f, 0.f, 0.f};
  for (int kt = 0; kt < 4; kt++) {
#pragma unroll
    for (int u = 0; u < 4; u++) {
      int c = u * 256 + tid;
      int row = c >> 3, ko = (c & 7) * 8;
      __builtin_amdgcn_global_load_lds(
          (const __attribute__((address_space(1))) unsigned int*)(S16 + (size_t)(mt * 128 + row) * 256 + kt * 64 + ko),
          (__attribute__((address_space(3))) unsigned int*)(lA + c * 8), 16, 0, 0);
      __builtin_amdgcn_global_load_lds(
          (const __attribute__((address_space(1))) unsigned int*)(WG16 + (size_t)(nc * 128 + row) * 256 + kt * 64 + ko),
          (__attribute__((address_space(3))) unsigned int*)(lB + c * 8), 16, 0, 0);
    }
    __syncthreads();
#pragma unroll
    for (int ks = 0; ks < 2; ks++) {
      bf16x8_t af[4], bfr[4];
#pragma unroll
      for (int i = 0; i < 4; i++) af[i] = *(const bf16x8_t*)(lA + (wm * 64 + i * 16 + l15) * 64 + ks * 32 + quad * 8);
#pragma unroll
      for (int j = 0; j < 4; j++) bfr[j] = *(const bf16x8_t*)(lB + (wn * 64 + j * 16 + l15) * 64 + ks * 32 + quad * 8);
#pragma unroll
      for (int i = 0; i < 4; i++)
#pragma unroll
        for (int j = 0; j < 4; j++)
          acc[i][j] = __builtin_amdgcn_mfma_f32_16x16x32_bf16(af[i], bfr[j], acc[i][j], 0, 0, 0);
    }
    __syncthreads();
  }
  float bj[4];
#pragma unroll
  for (int j = 0; j < 4; j++) bj[j] = wgb[nc * 128 + wn * 64 + j * 16 + l15];
#pragma unroll
  for (int i = 0; i < 4; i++) {
#pragma unroll
    for (int p = 0; p < 4; p++) {
      int rg = mt * 128 + wm * 64 + i * 16 + quad * 4 + p;
      float M = MZ[2 * rg];
      float iZ = 1.f / MZ[2 * rg + 1];
      size_t base = (size_t)rg * VT_ + nc * 128 + wn * 64 + l15;
#pragma unroll
      for (int j = 0; j < 4; j++)
        outp[base + j * 16] = expf(acc[i][j][p] + bj[j] - M) * iZ;
    }
  }
  __syncthreads();
  int nlo = nc * 128, nhi = nlo + 128;
  if (tid < 128) {
    int rg = mt * 128 + tid, b = rg >> 6;
    float M = MZ[2 * rg];
    float iZ = 1.f / MZ[2 * rg + 1];
    for (int s = 0; s < 128; s++) {
      int idx = encidx[b * 128 + s];
      if (idx >= nlo && idx < nhi) {
        float v = expf(psic[(size_t)rg * 128 + s] - M) * iZ;
        outp[(size_t)rg * VT_ + idx] += v;
      }
    }
  }
}

// ---------------------------------------------------------------- launch
extern "C" void kernel_launch(void* const* d_in, const int* in_sizes, int n_in,
                              void* d_out, int out_size, void* d_ws, size_t ws_size,
                              hipStream_t stream) {
  (void)in_sizes; (void)n_in; (void)out_size; (void)ws_size;
  const int*   inputs  = (const int*)d_in[0];
  const float* encoded = (const float*)d_in[1];
  const int*   encidx  = (const int*)d_in[2];
  const float* bridge  = (const float*)d_in[3];
  const float* embed   = (const float*)d_in[4];
  const float* wih     = (const float*)d_in[5];
  const float* whh     = (const float*)d_in[6];
  const float* bih     = (const float*)d_in[7];
  const float* bhh     = (const float*)d_in[8];
  const float* wg      = (const float*)d_in[9];
  const float* wgb     = (const float*)d_in[10];
  const float* wo      = (const float*)d_in[11];
  const float* wob     = (const float*)d_in[12];
  float* out = (float*)d_out;

  char* ws = (char*)d_ws;
  size_t off = 0;
  auto alloc = [&](size_t bytes) -> void* {
    void* p = ws + off;
    off += (bytes + 255) & ~(size_t)255;
    return p;
  };
  unsigned short* WG16 = (unsigned short*)alloc((size_t)32000 * 256 * 2);
  float* S32           = (float*)alloc((size_t)2048 * 256 * 4);
  unsigned short* S16  = (unsigned short*)alloc((size_t)2048 * 256 * 2);
  float* ENCSC         = (float*)alloc((size_t)4096 * 256 * 4);
  float* ENCIH         = (float*)alloc((size_t)4096 * 768 * 4);
  float* XG            = (float*)alloc((size_t)2048 * 768 * 4);
  float* S0            = (float*)alloc((size_t)32 * 256 * 4);
  float* PSIC          = (float*)alloc((size_t)2048 * 128 * 4);
  float* PMAX          = (float*)alloc((size_t)2048 * 256 * 4);
  float* PSUM          = (float*)alloc((size_t)2048 * 256 * 4);
  float* MZ            = (float*)alloc((size_t)2048 * 2 * 4);
  int*   CNT           = (int*)alloc((size_t)2048 * 4);

  k_zero<<<8, 256, 0, stream>>>(CNT, 2048);
  k_conv<<<1024, 256, 0, stream>>>(wg, WG16, 32000 * 256 / 4);
  k_enc<<<dim3(64, 4), 256, 0, stream>>>(encoded, wo, wob, ENCSC);
  k_s0<<<32, 256, 0, stream>>>(encoded, bridge, S0);
  k_xg<<<dim3(32, 12), 256, 0, stream>>>(embed, inputs, wih, bih, XG);
  k_encih<<<4096, 256, 0, stream>>>(encoded, wih, encidx, inputs, ENCIH);
  k_seq<<<448, 256, 0, stream>>>(whh, bhh, XG, ENCSC, ENCIH, encidx, inputs, S0, S32, S16, CNT);
  k_psic<<<256, 256, 0, stream>>>(S32, ENCSC, encidx, PSIC, PMAX, PSUM);
  k_p2a<<<dim3(250, 16), 256, 0, stream>>>(S16, WG16, wgb, PMAX, PSUM);
  k_p2m<<<2048, 256, 0, stream>>>(PMAX, PSUM, MZ);
  k_p2b<<<dim3(251, 16), 256, 0, stream>>>(S16, WG16, wgb, MZ, PSIC, encidx, out);
}

// Round 2
// 1240.654 us; speedup vs baseline: 1.6958x; 1.6958x over previous
//
#include <hip/hip_runtime.h>
#include <math.h>
#include <stdint.h>

// Problem constants
static const int VOC  = 32000;
static const int VT_  = 32100;

typedef __attribute__((ext_vector_type(8))) short bf16x8_t;
typedef __attribute__((ext_vector_type(4))) float f32x4_t;

__device__ __forceinline__ unsigned short f2bf(float f) {
  union { float f; unsigned int u; } v; v.f = f;
  unsigned int u = v.u;
  u = u + 0x7FFFu + ((u >> 16) & 1u);   // RNE
  return (unsigned short)(u >> 16);
}

// ---------------------------------------------------------------- utilities
__global__ void k_conv(const float* __restrict__ src, unsigned short* __restrict__ dst, int n4) {
  int i = blockIdx.x * blockDim.x + threadIdx.x;
  int stride = gridDim.x * blockDim.x;
  for (; i < n4; i += stride) {
    float4 f = ((const float4*)src)[i];
    ushort4 o;
    o.x = f2bf(f.x); o.y = f2bf(f.y); o.z = f2bf(f.z); o.w = f2bf(f.w);
    ((ushort4*)dst)[i] = o;
  }
}

// Transpose whh (768x256 row-major) -> wt4 float4 layout:
// wt4[k*192 + m] = {whh[4m][k], whh[4m+1][k], whh[4m+2][k], whh[4m+3][k]}
__global__ __launch_bounds__(256) void k_tr(const float* __restrict__ whh, float* __restrict__ wt4) {
  __shared__ float lds[4][257];
  int mg = blockIdx.x;     // 0..191 row-group
  int tid = threadIdx.x;
  int rr = tid >> 6, k4 = tid & 63;
  float4 v = ((const float4*)(whh + (size_t)(4 * mg + rr) * 256))[k4];
  lds[rr][k4 * 4 + 0] = v.x; lds[rr][k4 * 4 + 1] = v.y;
  lds[rr][k4 * 4 + 2] = v.z; lds[rr][k4 * 4 + 3] = v.w;
  __syncthreads();
  int k = tid;
  float4 o;
  o.x = lds[0][k]; o.y = lds[1][k]; o.z = lds[2][k]; o.w = lds[3][k];
  ((float4*)wt4)[(size_t)k * 192 + mg] = o;
}

// enc_scores = tanh(encoded @ Wo^T + Wo_b): M=4096 (b,s), N=256, K=512
__global__ __launch_bounds__(256) void k_enc(const float* __restrict__ enc,
                                             const float* __restrict__ wo,
                                             const float* __restrict__ wob,
                                             float* __restrict__ outp) {
  int bm = blockIdx.x, bn = blockIdx.y;
  int tid = threadIdx.x;
  int ti = tid & 15, tj = tid >> 4;
  int r0 = bm * 64 + ti * 4;
  int n0 = bn * 64 + tj * 4;
  const float4* A[4]; const float4* B[4];
#pragma unroll
  for (int i = 0; i < 4; i++) A[i] = (const float4*)(enc + (size_t)(r0 + i) * 512);
#pragma unroll
  for (int j = 0; j < 4; j++) B[j] = (const float4*)(wo + (size_t)(n0 + j) * 512);
  float acc[4][4];
#pragma unroll
  for (int i = 0; i < 4; i++)
#pragma unroll
    for (int j = 0; j < 4; j++) acc[i][j] = 0.f;
  for (int k = 0; k < 128; k++) {
    float4 a[4], b[4];
#pragma unroll
    for (int i = 0; i < 4; i++) a[i] = A[i][k];
#pragma unroll
    for (int j = 0; j < 4; j++) b[j] = B[j][k];
#pragma unroll
    for (int i = 0; i < 4; i++)
#pragma unroll
      for (int j = 0; j < 4; j++)
        acc[i][j] += a[i].x * b[j].x + a[i].y * b[j].y + a[i].z * b[j].z + a[i].w * b[j].w;
  }
#pragma unroll
  for (int i = 0; i < 4; i++)
#pragma unroll
    for (int j = 0; j < 4; j++)
      outp[(size_t)(r0 + i) * 256 + n0 + j] = tanhf(acc[i][j] + wob[n0 + j]);
}

// Xg = embed[inputs] @ Wih[:, :256]^T + b_ih: M=2048, N=768, K=256
__global__ __launch_bounds__(256) void k_xg(const float* __restrict__ embed,
                                            const int* __restrict__ inputs,
                                            const float* __restrict__ wih,
                                            const float* __restrict__ bih,
                                            float* __restrict__ xg) {
  int bm = blockIdx.x, bn = blockIdx.y;
  int tid = threadIdx.x;
  int ti = tid & 15, tj = tid >> 4;
  int r0 = bm * 64 + ti * 4;
  int n0 = bn * 64 + tj * 4;
  const float4* A[4]; const float4* B[4];
#pragma unroll
  for (int i = 0; i < 4; i++) A[i] = (const float4*)(embed + (size_t)inputs[r0 + i] * 256);
#pragma unroll
  for (int j = 0; j < 4; j++) B[j] = (const float4*)(wih + (size_t)(n0 + j) * 768);
  float acc[4][4];
#pragma unroll
  for (int i = 0; i < 4; i++)
#pragma unroll
    for (int j = 0; j < 4; j++) acc[i][j] = 0.f;
  for (int k = 0; k < 64; k++) {
    float4 a[4], b[4];
#pragma unroll
    for (int i = 0; i < 4; i++) a[i] = A[i][k];
#pragma unroll
    for (int j = 0; j < 4; j++) b[j] = B[j][k];
#pragma unroll
    for (int i = 0; i < 4; i++)
#pragma unroll
      for (int j = 0; j < 4; j++)
        acc[i][j] += a[i].x * b[j].x + a[i].y * b[j].y + a[i].z * b[j].z + a[i].w * b[j].w;
  }
#pragma unroll
  for (int i = 0; i < 4; i++)
#pragma unroll
    for (int j = 0; j < 4; j++)
      xg[(size_t)(r0 + i) * 768 + n0 + j] = acc[i][j] + bih[n0 + j];
}

// s0 = encoded[:, -1, :] @ bridge^T
__global__ __launch_bounds__(256) void k_s0(const float* __restrict__ enc,
                                            const float* __restrict__ bw,
                                            float* __restrict__ s0) {
  int b = blockIdx.x, h = threadIdx.x;
  const float4* a4 = (const float4*)(enc + ((size_t)b * 128 + 127) * 512);
  const float4* w4 = (const float4*)(bw + (size_t)h * 512);
  float acc = 0.f;
  for (int k = 0; k < 128; k++) {
    float4 a = a4[k], w = w4[k];
    acc += a.x * w.x + a.y * w.y + a.z * w.z + a.w * w.w;
  }
  s0[b * 256 + h] = acc;
}

// ENC_ih[b,s,:] = encoded[b,s,:] @ Wih[:, 256:768]^T  -- only where token ever matches
__global__ __launch_bounds__(256) void k_encih(const float* __restrict__ enc,
                                               const float* __restrict__ wih,
                                               const int* __restrict__ encidx,
                                               const int* __restrict__ inputs,
                                               float* __restrict__ encih) {
  __shared__ int flag;
  int bs = blockIdx.x;
  int b = bs >> 7;
  int tid = threadIdx.x;
  int idx = encidx[bs];
  if (tid < 64) {
    unsigned long long m = __ballot(inputs[b * 64 + tid] == idx);
    if (tid == 0) flag = (m != 0ULL);
  }
  __syncthreads();
  if (!flag) return;
  const float4* e4 = (const float4*)(enc + (size_t)bs * 512);
  for (int d = tid; d < 768; d += 256) {
    const float4* w4 = (const float4*)(wih + (size_t)d * 768 + 256);
    float acc = 0.f;
    for (int k = 0; k < 128; k++) {
      float4 e = e4[k], w = w4[k];
      acc += e.x * w.x + e.y * w.y + e.z * w.z + e.w * w.w;
    }
    encih[(size_t)bs * 768 + d] = acc;
  }
}

// -------------------------------------------------------- sequential GRU
// One block per batch row b: 768 threads = 4 K-quarters x 192 row-groups.
// W_hh streamed from L2 each step in transposed float4 layout (fully coalesced).
// All per-step state (s_t, gh partials, cw softmax) is block-local: NO
// cross-workgroup communication, no fences (per-XCD L2 coherence hazard).
__global__ __launch_bounds__(768, 1) void k_seq(
    const float* __restrict__ wt4,   // [256][192] float4 transposed whh
    const float* __restrict__ bhh,
    const float* __restrict__ xg, const float* __restrict__ encsc,
    const float* __restrict__ encih, const int* __restrict__ encidx,
    const int* __restrict__ inputs, const float* __restrict__ s0,
    float* __restrict__ S32, unsigned short* __restrict__ S16) {
  __shared__ float sbuf[256];
  __shared__ float ghp[4][768];
  __shared__ float psis[128];
  __shared__ int mlist[128];
  __shared__ int mcnt_sh;
  int b = blockIdx.x;
  int tid = threadIdx.x;
  int kq = tid / 192;           // K-quarter 0..3 (each wave lies in one kq)
  int m  = tid - kq * 192;      // row-group: rows 4m..4m+3
  int h = tid;                  // gate thread id (tid<256)
  float bR = 0.f, bZ = 0.f, bN = 0.f, ctxR = 0.f, ctxZ = 0.f, ctxN = 0.f;
  if (tid < 256) {
    bR = bhh[h]; bZ = bhh[256 + h]; bN = bhh[512 + h];
    sbuf[tid] = s0[b * 256 + tid];
  }
  __syncthreads();
  const float4* wbase = (const float4*)wt4 + (size_t)kq * 64 * 192 + m;
  for (int t = 0; t < 64; t++) {
    int r = b * 64 + t;
    // --- matvec partial: rows 4m..4m+3, k in [kq*64, kq*64+64)
    float4 acc = {0.f, 0.f, 0.f, 0.f};
    {
      const float4* sb4 = (const float4*)sbuf + kq * 16;
#pragma unroll 4
      for (int kk = 0; kk < 16; kk++) {
        float4 s4 = sb4[kk];
        const float4* w = wbase + (size_t)kk * 4 * 192;
        float4 w0 = w[0];
        float4 w1 = w[192];
        float4 w2 = w[384];
        float4 w3 = w[576];
        acc.x += s4.x * w0.x; acc.y += s4.x * w0.y; acc.z += s4.x * w0.z; acc.w += s4.x * w0.w;
        acc.x += s4.y * w1.x; acc.y += s4.y * w1.y; acc.z += s4.y * w1.z; acc.w += s4.y * w1.w;
        acc.x += s4.z * w2.x; acc.y += s4.z * w2.y; acc.z += s4.z * w2.z; acc.w += s4.z * w2.w;
        acc.x += s4.w * w3.x; acc.y += s4.w * w3.y; acc.z += s4.w * w3.z; acc.w += s4.w * w3.w;
      }
    }
    *(float4*)&ghp[kq][m * 4] = acc;
    __syncthreads();                                   // B1: ghp complete
    if (tid < 256) {
      float hr = ghp[0][h] + ghp[1][h] + ghp[2][h] + ghp[3][h] + bR;
      float hz = ghp[0][256 + h] + ghp[1][256 + h] + ghp[2][256 + h] + ghp[3][256 + h] + bZ;
      float hn = ghp[0][512 + h] + ghp[1][512 + h] + ghp[2][512 + h] + ghp[3][512 + h] + bN;
      const float* xr = xg + (size_t)r * 768;
      float gr = xr[h] + ctxR;
      float gz = xr[256 + h] + ctxZ;
      float gn = xr[512 + h] + ctxN;
      float rgate = 1.f / (1.f + expf(-(gr + hr)));
      float zgate = 1.f / (1.f + expf(-(gz + hz)));
      float ngate = tanhf(gn + rgate * hn);
      float sold = sbuf[h];
      float snew = (1.f - zgate) * ngate + zgate * sold;
      S32[(size_t)r * 256 + h] = snew;
      S16[(size_t)r * 256 + h] = f2bf(snew);
      sbuf[h] = snew;                                  // own-element RMW, safe
    }
    if (tid == 256) mcnt_sh = 0;
    __syncthreads();                                   // B2: s_t complete
    if (t == 63) break;
    // --- matched-position copy-attention for ctx(t) -> used at step t+1
    int inp_t = inputs[b * 64 + t];
    if (tid < 128 && encidx[b * 128 + tid] == inp_t) {
      int p = atomicAdd(&mcnt_sh, 1);
      mlist[p] = tid;
    }
    __syncthreads();                                   // B3
    int mc = mcnt_sh;
    if (mc > 0) {
      int wv = tid >> 6, ln = tid & 63;
      for (int j = wv; j < mc; j += 12) {
        int s = mlist[j];
        const float4* e4 = (const float4*)(encsc + (size_t)(b * 128 + s) * 256);
        float4 ev = e4[ln];
        float4 sv = ((const float4*)sbuf)[ln];
        float v = ev.x * sv.x + ev.y * sv.y + ev.z * sv.z + ev.w * sv.w;
#pragma unroll
        for (int off = 32; off >= 1; off >>= 1) v += __shfl_down(v, off);
        if (ln == 0) psis[j] = v + (encidx[b * 128 + s] == 0 ? -1000.f : 0.f);
      }
      __syncthreads();                                 // B4
      if (tid == 0) {
        float mx = -3e38f;
        for (int j = 0; j < mc; j++) mx = fmaxf(mx, psis[j]);
        if (mx < -500.f) {       // all matches are pads -> reference cw == 0
          for (int j = 0; j < mc; j++) psis[j] = 0.f;
        } else {
          float ss = 0.f;
          for (int j = 0; j < mc; j++) { float e = expf(psis[j] - mx); psis[j] = e; ss += e; }
          float rs = 1.f / ss;
          for (int j = 0; j < mc; j++) psis[j] *= rs;
        }
      }
      __syncthreads();                                 // B5
      if (tid < 256) {
        ctxR = 0.f; ctxZ = 0.f; ctxN = 0.f;
        for (int j = 0; j < mc; j++) {
          float c = psis[j];
          const float* e = encih + (size_t)(b * 128 + mlist[j]) * 768;
          ctxR += c * e[h]; ctxZ += c * e[256 + h]; ctxN += c * e[512 + h];
        }
      }
    } else {
      if (tid < 256) { ctxR = 0.f; ctxZ = 0.f; ctxN = 0.f; }
    }
    __syncthreads();                                   // B6
  }
}

// psic = S32 x ENCSC^T (batched, block-diagonal) + pad mask. grid (32 b, 2 ny)
__global__ __launch_bounds__(256) void k_psic(const float* __restrict__ S32,
                                              const float* __restrict__ encsc,
                                              const int* __restrict__ encidx,
                                              float* __restrict__ psic) {
  int b = blockIdx.x, ny = blockIdx.y;
  int tid = threadIdx.x;
  int ti = tid & 15, tj = tid >> 4;
  int r0 = b * 64 + ti * 4;      // global (b,t) row
  int s0 = ny * 64 + tj * 4;
  const float4* A[4]; const float4* B[4];
#pragma unroll
  for (int i = 0; i < 4; i++) A[i] = (const float4*)(S32 + (size_t)(r0 + i) * 256);
#pragma unroll
  for (int j = 0; j < 4; j++) B[j] = (const float4*)(encsc + (size_t)(b * 128 + s0 + j) * 256);
  float acc[4][4];
#pragma unroll
  for (int i = 0; i < 4; i++)
#pragma unroll
    for (int j = 0; j < 4; j++) acc[i][j] = 0.f;
  for (int k = 0; k < 64; k++) {
    float4 a[4], bb[4];
#pragma unroll
    for (int i = 0; i < 4; i++) a[i] = A[i][k];
#pragma unroll
    for (int j = 0; j < 4; j++) bb[j] = B[j][k];
#pragma unroll
    for (int i = 0; i < 4; i++)
#pragma unroll
      for (int j = 0; j < 4; j++)
        acc[i][j] += a[i].x * bb[j].x + a[i].y * bb[j].y + a[i].z * bb[j].z + a[i].w * bb[j].w;
  }
#pragma unroll
  for (int i = 0; i < 4; i++)
#pragma unroll
    for (int j = 0; j < 4; j++) {
      float v = acc[i][j] + (encidx[b * 128 + s0 + j] == 0 ? -1000.f : 0.f);
      psic[(size_t)(r0 + i) * 128 + s0 + j] = v;
    }
}

// psi_g pass A: 128x128 bf16 MFMA tile -> per-row (max, sumexp) partials
__global__ __launch_bounds__(256) void k_p2a(const unsigned short* __restrict__ S16,
                                             const unsigned short* __restrict__ WG16,
                                             const float* __restrict__ wgb,
                                             float* __restrict__ pmax,
                                             float* __restrict__ psum) {
  __shared__ unsigned short lA[128 * 64];
  __shared__ unsigned short lB[128 * 64];
  __shared__ float redm[128][2];
  __shared__ float reds[128][2];
  int nc = blockIdx.x, mt = blockIdx.y;
  int tid = threadIdx.x;
  int wid = tid >> 6, lane = tid & 63;
  int wm = wid >> 1, wn = wid & 1;
  int quad = lane >> 4, l15 = lane & 15;
  f32x4_t acc[4][4];
#pragma unroll
  for (int i = 0; i < 4; i++)
#pragma unroll
    for (int j = 0; j < 4; j++) acc[i][j] = (f32x4_t){0.f, 0.f, 0.f, 0.f};
  for (int kt = 0; kt < 4; kt++) {
#pragma unroll
    for (int u = 0; u < 4; u++) {
      int c = u * 256 + tid;
      int row = c >> 3, ko = (c & 7) * 8;
      __builtin_amdgcn_global_load_lds(
          (const __attribute__((address_space(1))) unsigned int*)(S16 + (size_t)(mt * 128 + row) * 256 + kt * 64 + ko),
          (__attribute__((address_space(3))) unsigned int*)(lA + c * 8), 16, 0, 0);
      __builtin_amdgcn_global_load_lds(
          (const __attribute__((address_space(1))) unsigned int*)(WG16 + (size_t)(nc * 128 + row) * 256 + kt * 64 + ko),
          (__attribute__((address_space(3))) unsigned int*)(lB + c * 8), 16, 0, 0);
    }
    __syncthreads();
#pragma unroll
    for (int ks = 0; ks < 2; ks++) {
      bf16x8_t af[4], bfr[4];
#pragma unroll
      for (int i = 0; i < 4; i++) af[i] = *(const bf16x8_t*)(lA + (wm * 64 + i * 16 + l15) * 64 + ks * 32 + quad * 8);
#pragma unroll
      for (int j = 0; j < 4; j++) bfr[j] = *(const bf16x8_t*)(lB + (wn * 64 + j * 16 + l15) * 64 + ks * 32 + quad * 8);
#pragma unroll
      for (int i = 0; i < 4; i++)
#pragma unroll
        for (int j = 0; j < 4; j++)
          acc[i][j] = __builtin_amdgcn_mfma_f32_16x16x32_bf16(af[i], bfr[j], acc[i][j], 0, 0, 0);
    }
    __syncthreads();
  }
  float bj[4];
#pragma unroll
  for (int j = 0; j < 4; j++) bj[j] = wgb[nc * 128 + wn * 64 + j * 16 + l15];
#pragma unroll
  for (int i = 0; i < 4; i++) {
#pragma unroll
    for (int p = 0; p < 4; p++) {
      float m = -3e38f;
#pragma unroll
      for (int j = 0; j < 4; j++) m = fmaxf(m, acc[i][j][p] + bj[j]);
#pragma unroll
      for (int off = 1; off < 16; off <<= 1) m = fmaxf(m, __shfl_xor(m, off));
      float sum = 0.f;
#pragma unroll
      for (int j = 0; j < 4; j++) sum += expf(acc[i][j][p] + bj[j] - m);
#pragma unroll
      for (int off = 1; off < 16; off <<= 1) sum += __shfl_xor(sum, off);
      if (l15 == 0) {
        int row = wm * 64 + i * 16 + quad * 4 + p;
        redm[row][wn] = m;
        reds[row][wn] = sum;
      }
    }
  }
  __syncthreads();
  if (tid < 128) {
    float m0 = redm[tid][0], m1 = redm[tid][1];
    float M = fmaxf(m0, m1);
    float S = reds[tid][0] * expf(m0 - M) + reds[tid][1] * expf(m1 - M);
    int rg = mt * 128 + tid;
    pmax[(size_t)rg * 256 + nc] = M;
    psum[(size_t)rg * 256 + nc] = S;
  }
}

// merge 250 chunk partials + psi_c chunk (computed inline from psic) -> (M, Z)
__global__ __launch_bounds__(256) void k_p2m(const float* __restrict__ pmax,
                                             const float* __restrict__ psum,
                                             const float* __restrict__ psic,
                                             float* __restrict__ MZ) {
  __shared__ float rm[4], rs[4];
  __shared__ float cMs, cSs;
  __shared__ float Msh;
  int r = blockIdx.x, tid = threadIdx.x;
  // psi_c chunk partial over the 128 positions
  float pv = (tid < 128) ? psic[(size_t)r * 128 + tid] : -3e38f;
  float pm = pv;
#pragma unroll
  for (int off = 32; off >= 1; off >>= 1) pm = fmaxf(pm, __shfl_xor(pm, off));
  if (tid < 128 && (tid & 63) == 0) rm[tid >> 6] = pm;
  __syncthreads();
  float cMv = fmaxf(rm[0], rm[1]);
  float pe = (tid < 128) ? expf(pv - cMv) : 0.f;
#pragma unroll
  for (int off = 32; off >= 1; off >>= 1) pe += __shfl_xor(pe, off);
  if (tid < 128 && (tid & 63) == 0) rs[tid >> 6] = pe;
  __syncthreads();
  if (tid == 0) { cMs = cMv; cSs = rs[0] + rs[1]; }
  __syncthreads();
  // merge 250 MFMA-chunk partials + the psi_c chunk
  float m = (tid < 250) ? pmax[(size_t)r * 256 + tid] : ((tid == 250) ? cMs : -3e38f);
  float mm = m;
#pragma unroll
  for (int off = 32; off >= 1; off >>= 1) mm = fmaxf(mm, __shfl_xor(mm, off));
  if ((tid & 63) == 0) rm[tid >> 6] = mm;
  __syncthreads();
  if (tid == 0) Msh = fmaxf(fmaxf(rm[0], rm[1]), fmaxf(rm[2], rm[3]));
  __syncthreads();
  float M = Msh;
  float zv = (tid < 250) ? psum[(size_t)r * 256 + tid] : ((tid == 250) ? cSs : 0.f);
  float z = zv * expf(m - M);
#pragma unroll
  for (int off = 32; off >= 1; off >>= 1) z += __shfl_xor(z, off);
  if ((tid & 63) == 0) rs[tid >> 6] = z;
  __syncthreads();
  if (tid == 0) {
    MZ[2 * r] = M;
    MZ[2 * r + 1] = rs[0] + rs[1] + rs[2] + rs[3];
  }
}

// pass B: recompute psi_g tile, p = exp(psi-M)/Z, write out; chunk-local scatter
__global__ __launch_bounds__(256) void k_p2b(const unsigned short* __restrict__ S16,
                                             const unsigned short* __restrict__ WG16,
                                             const float* __restrict__ wgb,
                                             const float* __restrict__ MZ,
                                             const float* __restrict__ psic,
                                             const int* __restrict__ encidx,
                                             float* __restrict__ outp) {
  int nc = blockIdx.x, mt = blockIdx.y;
  int tid = threadIdx.x;
  if (nc == 250) {  // OOV columns [32000, 32100)
    for (int p = tid; p < 128 * 100; p += 256) {
      int rl = p / 100, c2 = p - rl * 100;
      int rg = mt * 128 + rl;
      outp[(size_t)rg * VT_ + 32000 + c2] = 1e-4f;
    }
    __syncthreads();
    if (tid < 128) {
      int rg = mt * 128 + tid, b = rg >> 6;
      float M = MZ[2 * rg];
      float iZ = 1.f / MZ[2 * rg + 1];
      for (int s = 0; s < 128; s++) {
        int idx = encidx[b * 128 + s];
        if (idx >= 32000) {
          float v = expf(psic[(size_t)rg * 128 + s] - M) * iZ;
          outp[(size_t)rg * VT_ + idx] += v;
        }
      }
    }
    return;
  }
  __shared__ unsigned short lA[128 * 64];
  __shared__ unsigned short lB[128 * 64];
  int wid = tid >> 6, lane = tid & 63;
  int wm = wid >> 1, wn = wid & 1;
  int quad = lane >> 4, l15 = lane & 15;
  f32x4_t acc[4][4];
#pragma unroll
  for (int i = 0; i < 4; i++)
#pragma unroll
    for (int j = 0; j < 4; j++) acc[i][j] = (f32x4_t){0.f, 0.f, 0.f, 0.f};
  for (int kt = 0; kt < 4; kt++) {
#pragma unroll
    for (int u = 0; u < 4; u++) {
      int c = u * 256 + tid;
      int row = c >> 3, ko = (c & 7) * 8;
      __builtin_amdgcn_global_load_lds(
          (const __attribute__((address_space(1))) unsigned int*)(S16 + (size_t)(mt * 128 + row) * 256 + kt * 64 + ko),
          (__attribute__((address_space(3))) unsigned int*)(lA + c * 8), 16, 0, 0);
      __builtin_amdgcn_global_load_lds(
          (const __attribute__((address_space(1))) unsigned int*)(WG16 + (size_t)(nc * 128 + row) * 256 + kt * 64 + ko),
          (__attribute__((address_space(3))) unsigned int*)(lB + c * 8), 16, 0, 0);
    }
    __syncthreads();
#pragma unroll
    for (int ks = 0; ks < 2; ks++) {
      bf16x8_t af[4], bfr[4];
#pragma unroll
      for (int i = 0; i < 4; i++) af[i] = *(const bf16x8_t*)(lA + (wm * 64 + i * 16 + l15) * 64 + ks * 32 + quad * 8);
#pragma unroll
      for (int j = 0; j < 4; j++) bfr[j] = *(const bf16x8_t*)(lB + (wn * 64 + j * 16 + l15) * 64 + ks * 32 + quad * 8);
#pragma unroll
      for (int i = 0; i < 4; i++)
#pragma unroll
        for (int j = 0; j < 4; j++)
          acc[i][j] = __builtin_amdgcn_mfma_f32_16x16x32_bf16(af[i], bfr[j], acc[i][j], 0, 0, 0);
    }
    __syncthreads();
  }
  float bj[4];
#pragma unroll
  for (int j = 0; j < 4; j++) bj[j] = wgb[nc * 128 + wn * 64 + j * 16 + l15];
#pragma unroll
  for (int i = 0; i < 4; i++) {
#pragma unroll
    for (int p = 0; p < 4; p++) {
      int rg = mt * 128 + wm * 64 + i * 16 + quad * 4 + p;
      float M = MZ[2 * rg];
      float iZ = 1.f / MZ[2 * rg + 1];
      size_t base = (size_t)rg * VT_ + nc * 128 + wn * 64 + l15;
#pragma unroll
      for (int j = 0; j < 4; j++)
        outp[base + j * 16] = expf(acc[i][j][p] + bj[j] - M) * iZ;
    }
  }
  __syncthreads();
  int nlo = nc * 128, nhi = nlo + 128;
  if (tid < 128) {
    int rg = mt * 128 + tid, b = rg >> 6;
    float M = MZ[2 * rg];
    float iZ = 1.f / MZ[2 * rg + 1];
    for (int s = 0; s < 128; s++) {
      int idx = encidx[b * 128 + s];
      if (idx >= nlo && idx < nhi) {
        float v = expf(psic[(size_t)rg * 128 + s] - M) * iZ;
        outp[(size_t)rg * VT_ + idx] += v;
      }
    }
  }
}

// ---------------------------------------------------------------- launch
extern "C" void kernel_launch(void* const* d_in, const int* in_sizes, int n_in,
                              void* d_out, int out_size, void* d_ws, size_t ws_size,
                              hipStream_t stream) {
  (void)in_sizes; (void)n_in; (void)out_size; (void)ws_size;
  const int*   inputs  = (const int*)d_in[0];
  const float* encoded = (const float*)d_in[1];
  const int*   encidx  = (const int*)d_in[2];
  const float* bridge  = (const float*)d_in[3];
  const float* embed   = (const float*)d_in[4];
  const float* wih     = (const float*)d_in[5];
  const float* whh     = (const float*)d_in[6];
  const float* bih     = (const float*)d_in[7];
  const float* bhh     = (const float*)d_in[8];
  const float* wg      = (const float*)d_in[9];
  const float* wgb     = (const float*)d_in[10];
  const float* wo      = (const float*)d_in[11];
  const float* wob     = (const float*)d_in[12];
  float* out = (float*)d_out;

  char* ws = (char*)d_ws;
  size_t off = 0;
  auto alloc = [&](size_t bytes) -> void* {
    void* p = ws + off;
    off += (bytes + 255) & ~(size_t)255;
    return p;
  };
  unsigned short* WG16 = (unsigned short*)alloc((size_t)32000 * 256 * 2);
  float* WT4           = (float*)alloc((size_t)768 * 256 * 4);
  float* S32           = (float*)alloc((size_t)2048 * 256 * 4);
  unsigned short* S16  = (unsigned short*)alloc((size_t)2048 * 256 * 2);
  float* ENCSC         = (float*)alloc((size_t)4096 * 256 * 4);
  float* ENCIH         = (float*)alloc((size_t)4096 * 768 * 4);
  float* XG            = (float*)alloc((size_t)2048 * 768 * 4);
  float* S0            = (float*)alloc((size_t)32 * 256 * 4);
  float* PSIC          = (float*)alloc((size_t)2048 * 128 * 4);
  float* PMAX          = (float*)alloc((size_t)2048 * 256 * 4);
  float* PSUM          = (float*)alloc((size_t)2048 * 256 * 4);
  float* MZ            = (float*)alloc((size_t)2048 * 2 * 4);

  k_conv<<<1024, 256, 0, stream>>>(wg, WG16, 32000 * 256 / 4);
  k_tr<<<192, 256, 0, stream>>>(whh, WT4);
  k_enc<<<dim3(64, 4), 256, 0, stream>>>(encoded, wo, wob, ENCSC);
  k_s0<<<32, 256, 0, stream>>>(encoded, bridge, S0);
  k_xg<<<dim3(32, 12), 256, 0, stream>>>(embed, inputs, wih, bih, XG);
  k_encih<<<4096, 256, 0, stream>>>(encoded, wih, encidx, inputs, ENCIH);
  k_seq<<<32, 768, 0, stream>>>(WT4, bhh, XG, ENCSC, ENCIH, encidx, inputs, S0, S32, S16);
  k_psic<<<dim3(32, 2), 256, 0, stream>>>(S32, ENCSC, encidx, PSIC);
  k_p2a<<<dim3(250, 16), 256, 0, stream>>>(S16, WG16, wgb, PMAX, PSUM);
  k_p2m<<<2048, 256, 0, stream>>>(PMAX, PSUM, PSIC, MZ);
  k_p2b<<<dim3(251, 16), 256, 0, stream>>>(S16, WG16, wgb, MZ, PSIC, encidx, out);
}